// Round 18
// baseline (290.820 us; speedup 1.0000x reference)
//
#include <hip/hip_runtime.h>
#include <hip/hip_bf16.h>

// TtAttention: x(2048,4096) -> QKV proj -> RoPE -> windowed causal GQA attention -> O proj.
// GEMMs: BK=64 flat K-tile interior, A 2-buf / B 3-buf glds, counted vmcnt boundary
// (never 0 mid-loop), 1 barrier/K-tile, 256 blocks, bm = XCD (A-panel L2-resident),
// waves 4Mx2N. QKV: BM=256 BN=192. O-proj: BM=256 BN=128 (retiled to QKV geometry).
// attn: 8-wave blocks, single-buffered K/V, 3 blocks/CU; fused wo cast.

typedef __attribute__((ext_vector_type(8))) short short8;
typedef __attribute__((ext_vector_type(4))) float floatx4;
typedef unsigned short u16;
typedef unsigned int u32;

__device__ __forceinline__ u16 f2bf(float f) {
  u32 u = __builtin_bit_cast(u32, f);
  u32 r = u + 0x7FFFu + ((u >> 16) & 1u);
  return (u16)(r >> 16);
}

#define GLDS16(g, l)                                                     \
  __builtin_amdgcn_global_load_lds(                                      \
      (const __attribute__((address_space(1))) u32*)(g),                 \
      (__attribute__((address_space(3))) u32*)(l), 16, 0, 0)

#define SB() __builtin_amdgcn_sched_barrier(0)

// ---------------------------------------------------------------- cast ----
// x + wq/wk/wv (wo folded into attn).
__global__ __launch_bounds__(256) void cast_in(
    const float* __restrict__ x, const float* __restrict__ wq,
    const float* __restrict__ wk, const float* __restrict__ wv,
    u16* __restrict__ xb, u16* __restrict__ wqb, u16* __restrict__ wkb,
    u16* __restrict__ wvb) {
  const int tid = blockIdx.x * blockDim.x + threadIdx.x;
  const int stride = gridDim.x * blockDim.x;
  auto seg = [&](const float* __restrict__ in, u16* __restrict__ out, int n4) {
    for (int i = tid; i < n4; i += stride) {
      float4 v = ((const float4*)in)[i];
      ushort4 o;
      o.x = f2bf(v.x); o.y = f2bf(v.y); o.z = f2bf(v.z); o.w = f2bf(v.w);
      ((ushort4*)out)[i] = o;
    }
  };
  seg(x, xb, 2097152);
  seg(wq, wqb, 4194304);
  seg(wk, wkb, 1048576);
  seg(wv, wvb, 1048576);
}

// ---------------------------------------------------------------- GEMM ----
// C[m][n] = sum_k A[m][k]*B[n][k].  8 waves (4M x 2N, WR=64), BM=256, BK=64.
// IS_QKV=1: BN=192 (WC=96), B = concat[wq;wk;wv], per-frag epilogue.
// IS_QKV=0: BN=128 (WC=64), B = wo, fp32 store.
// Both: grid 8m x 32n = 256 blocks; bm = blockIdx.x & 7 (= XCD, A-panel resident).
// LDS: A x2 bufs, B x3 bufs, 128B rows, slot^=(row&7).
// Flat K-tile: reads(kh0) | stage A(t+1) | MFMA(kh0) | reads(kh1) | stage B(t+2)
// | MFMA(kh1); SB-fenced; counted vmcnt(NCB) retires {B,A}(t+1), keeps B(t+2) in flight.
template <int IS_QKV>
__global__ __launch_bounds__(512, 2) void gemm_t(
    const u16* __restrict__ A, const u16* __restrict__ B, void* __restrict__ Cq,
    u16* __restrict__ Ck, u16* __restrict__ Cv, const float* __restrict__ fcos,
    const float* __restrict__ fsin) {
  constexpr int BM = 256;
  constexpr int BN = IS_QKV ? 192 : 128;
  constexpr int WR = 64;                  // rows per wave (4M)
  constexpr int WC = IS_QKV ? 96 : 64;    // cols per wave (2N)
  constexpr int MFR = WR / 16;            // 4
  constexpr int NFR = WC / 16;            // 6 or 4
  constexpr int ASZ = BM * 128;           // A buffer bytes (32KB)
  constexpr int BSZ = BN * 128;           // B buffer bytes (24KB or 16KB)
  constexpr int NCA = ASZ / 8192;         // 4
  constexpr int NCB = BSZ / 8192;         // 3 or 2
  __shared__ u16 lds[(2 * ASZ + 3 * BSZ) / 2];
  const int K = 4096;

  const int bm = blockIdx.x & 7;          // XCD owns one 256-row A-panel
  const int bx = blockIdx.x >> 3;
  const int m0 = bm * BM, n0 = bx * BN;

  const int t = threadIdx.x, l = t & 63, w = t >> 6;
  const int li = l & 15, g = l >> 4;
  const int wm = w >> 1, wn = w & 1;      // 4M x 2N

  // staging: 8KB chunk = 64 rows x 128B; thread t -> row (t>>3), slot (t&7);
  // pre-swizzled global source slot = (t&7) ^ (row&7).
  const int srow = t >> 3;
  const int sslot = (t & 7) ^ (srow & 7);
  const u16* gA = A + (size_t)(m0 + srow) * K + sslot * 8;
  const u16* gB = B + (size_t)(n0 + srow) * K + sslot * 8;
  const int dst = t * 16;

  char* A0p = (char*)lds;
  char* A1p = A0p + ASZ;
  char* B0p = A0p + 2 * ASZ;
  char* B1p = B0p + BSZ;
  char* B2p = B1p + BSZ;

  auto stA = [&](char* base, int kt, int c) {
    GLDS16(gA + (size_t)c * 64 * K + kt, base + c * 8192 + dst);
  };
  auto stB = [&](char* base, int kt, int c) {
    GLDS16(gB + (size_t)c * 64 * K + kt, base + c * 8192 + dst);
  };

  // ds_read offsets (relative to buffer base): row r, k-group (kh*4+g),
  // swizzled slot = (kh*4+g) ^ (r&7).
  int offA[2][MFR], offB[2][NFR];
#pragma unroll
  for (int kh = 0; kh < 2; kh++) {
#pragma unroll
    for (int mf = 0; mf < MFR; mf++) {
      int r = wm * WR + mf * 16 + li;
      offA[kh][mf] = r * 128 + ((((kh << 2) | g) ^ (r & 7)) << 4);
    }
#pragma unroll
    for (int nf = 0; nf < NFR; nf++) {
      int r = wn * WC + nf * 16 + li;
      offB[kh][nf] = r * 128 + ((((kh << 2) | g) ^ (r & 7)) << 4);
    }
  }

  floatx4 acc[MFR][NFR] = {};
  const int NT = K / 64;  // 64 K-tiles

  // prologue: B(0)->B0, A(0)->A0, B(1)->B1; counted wait (B1 stays in flight)
#pragma unroll
  for (int c = 0; c < NCB; c++) stB(B0p, 0, c);
#pragma unroll
  for (int c = 0; c < NCA; c++) stA(A0p, 0, c);
#pragma unroll
  for (int c = 0; c < NCB; c++) stB(B1p, 64, c);
  if constexpr (IS_QKV) asm volatile("s_waitcnt vmcnt(3)" ::: "memory");
  else                  asm volatile("s_waitcnt vmcnt(2)" ::: "memory");
  __builtin_amdgcn_s_barrier();

  for (int tt = 0; tt < NT; ++tt) {
    SB();  // region start: nothing crosses the barrier above
    const char* Ac = A0p;
    const char* Bc = B0p;
    const int kt1 = (tt + 1) * 64, kt2 = (tt + 2) * 64;
    const bool s1 = (tt + 1 < NT), s2 = (tt + 2 < NT);

    short8 a0[MFR], b0[NFR], a1[MFR], b1[NFR];
    // ---- k-half 0: reads, stage A(t+1), MFMA
#pragma unroll
    for (int nf = 0; nf < NFR; nf++) b0[nf] = *(const short8*)(Bc + offB[0][nf]);
#pragma unroll
    for (int mf = 0; mf < MFR; mf++) a0[mf] = *(const short8*)(Ac + offA[0][mf]);
    if (s1) {
#pragma unroll
      for (int c = 0; c < NCA; c++) stA(A1p, kt1, c);
    }
#pragma unroll
    for (int mf = 0; mf < MFR; mf++)
#pragma unroll
      for (int nf = 0; nf < NFR; nf++)
        acc[mf][nf] = __builtin_amdgcn_mfma_f32_16x16x32_bf16(a0[mf], b0[nf], acc[mf][nf], 0, 0, 0);
    // ---- k-half 1: reads (hoist under kh0 MFMAs), stage B(t+2), MFMA
#pragma unroll
    for (int nf = 0; nf < NFR; nf++) b1[nf] = *(const short8*)(Bc + offB[1][nf]);
#pragma unroll
    for (int mf = 0; mf < MFR; mf++) a1[mf] = *(const short8*)(Ac + offA[1][mf]);
    if (s2) {
#pragma unroll
      for (int c = 0; c < NCB; c++) stB(B2p, kt2, c);
    }
#pragma unroll
    for (int mf = 0; mf < MFR; mf++)
#pragma unroll
      for (int nf = 0; nf < NFR; nf++)
        acc[mf][nf] = __builtin_amdgcn_mfma_f32_16x16x32_bf16(a1[mf], b1[nf], acc[mf][nf], 0, 0, 0);
    SB();
    if (s2) {
      if constexpr (IS_QKV) asm volatile("s_waitcnt vmcnt(3)" ::: "memory");
      else                  asm volatile("s_waitcnt vmcnt(2)" ::: "memory");
    } else if (s1) {
      asm volatile("s_waitcnt vmcnt(0)" ::: "memory");
    }
    __builtin_amdgcn_s_barrier();

    // rotate buffers: A swap; B rotate by one
    char* tmpA = A0p; A0p = A1p; A1p = tmpA;
    char* tmpB = B0p; B0p = B1p; B1p = B2p; B2p = tmpB;
  }

  const float scale = 0.08838834764831845f;  // 128^-0.5
#pragma unroll
  for (int mf = 0; mf < MFR; mf++) {
#pragma unroll
    for (int nf = 0; nf < NFR; nf++) {
      const int row0 = m0 + wm * WR + mf * 16 + 4 * g;
      const int c = n0 + wn * WC + nf * 16 + li;
      if constexpr (!IS_QKV) {
        float* Cf = (float*)Cq;
#pragma unroll
        for (int r = 0; r < 4; r++) Cf[(size_t)(row0 + r) * 4096 + c] = acc[mf][nf][r];
      } else {
        // region is uniform across the 16-lane fragment (boundaries % 16 == 0)
        if (c < 5120) {  // Q or K: RoPE (+scale for Q)
          const int hd = c & 127;
          const int pp = hd >> 1;
          const bool even = (hd & 1) == 0;
#pragma unroll
          for (int r = 0; r < 4; r++) {
            const int row = row0 + r;
            float cv = fcos[row * 64 + pp];
            float sv = fsin[row * 64 + pp];
            float v = acc[mf][nf][r];
            float pv = __shfl_xor(v, 1);
            float o = even ? (v * cv - pv * sv) : (pv * sv + v * cv);
            if (c < 4096) {
              ((u16*)Cq)[(size_t)row * 4096 + c] = f2bf(o * scale);
            } else {
              Ck[(size_t)row * 1024 + (c - 4096)] = f2bf(o);
            }
          }
        } else {  // V: transposed bf16 store to V^T (ld 2048)
          u32 lo = (u32)f2bf(acc[mf][nf][0]) | ((u32)f2bf(acc[mf][nf][1]) << 16);
          u32 hi = (u32)f2bf(acc[mf][nf][2]) | ((u32)f2bf(acc[mf][nf][3]) << 16);
          uint2 val; val.x = lo; val.y = hi;
          *(uint2*)(&Cv[(size_t)(c - 5120) * 2048 + row0]) = val;
        }
      }
    }
  }
}

// ----------------------------------------------------------- attention ----
// Q (2048,4096) bf16 (RoPE'd, pre-scaled), K (2048,1024) bf16 (RoPE'd),
// Vt (1024,2048) bf16 = V^T. O (2048,4096) bf16.
// 8-wave blocks: grid (S/128, H) = (16,32); wave w owns q rows [q0+16w, +16).
// SINGLE-buffered K/V tiles (KVBLK=64) shared by all 8 waves; 50KB LDS ->
// 3 blocks/CU (LDS-limited, ~24 waves/CU) — TLP replaces the double-buffer.
// launch_bounds (512,2): let the allocator breathe (r16 lesson).
// Per tile: stage -> vmcnt(0) -> barrier -> compute -> barrier.
// FUSED: wo fp32->bf16 cast at kernel top (512 blk x 512 thr x 16 float4).
__global__ __launch_bounds__(512, 2) void attn_kernel(const u16* __restrict__ Q,
                                                      const u16* __restrict__ K,
                                                      const u16* __restrict__ Vt,
                                                      u16* __restrict__ O,
                                                      const float* __restrict__ wo,
                                                      u16* __restrict__ wob) {
  __shared__ u16 Ks[64 * 128];   // [k][d], 256B rows, slot ^= row&7
  __shared__ u16 Vs[128 * 64];   // [d][k], 128B rows, slot ^= row&7
  __shared__ u16 Ps[8][16 * 68]; // per-wave P relayout, stride 68 (136B)

  // ---- fused wo cast: 512 blocks x 512 thr x 16 float4 = 16.7M floats ----
  {
    const int gid = (blockIdx.y * gridDim.x + blockIdx.x) * 512 + threadIdx.x;
#pragma unroll 4
    for (int i = 0; i < 16; i++) {
      const size_t idx = (size_t)gid + (size_t)i * 262144;
      float4 v = ((const float4*)wo)[idx];
      ushort4 o;
      o.x = f2bf(v.x); o.y = f2bf(v.y); o.z = f2bf(v.z); o.w = f2bf(v.w);
      ((ushort4*)wob)[idx] = o;
    }
  }

  const int t = threadIdx.x, l = t & 63, w = t >> 6;   // w in 0..7
  const int li = l & 15, g = l >> 4;
  const int q0 = blockIdx.x * 128;
  const int h = blockIdx.y;
  const int kvh = h >> 2;
  const int qw = q0 + w * 16;

  short8 qf[4];
  {
    const u16* qp = Q + (size_t)(qw + li) * 4096 + h * 128 + g * 8;
#pragma unroll
    for (int kk = 0; kk < 4; kk++) qf[kk] = *(const short8*)(qp + kk * 32);
  }

  // staging: per wave 2 chunks of 1KB for K (16KB) and V (16KB)
  const u16* gK[2];
  const u16* gV[2];
  int ldsOff[2];
#pragma unroll
  for (int i = 0; i < 2; i++) {
    int rK = (2 * w + i) * 4 + (l >> 4);           // K rows (256B rows)
    int sK = (l & 15) ^ (rK & 7);
    gK[i] = K + (size_t)rK * 1024 + kvh * 128 + sK * 8;
    int rV = (2 * w + i) * 8 + (l >> 3);           // V^T rows (128B rows)
    int sV = (l & 7) ^ (rV & 7);
    gV[i] = Vt + (size_t)(kvh * 128 + rV) * 2048 + sV * 8;
    ldsOff[i] = (2 * w + i) * 1024;
  }

  int offK[4][4];
#pragma unroll
  for (int n = 0; n < 4; n++) {
    int r = 16 * n + li;
#pragma unroll
    for (int kk = 0; kk < 4; kk++)
      offK[n][kk] = r * 256 + (((kk * 4 + g) ^ (r & 7)) << 4);
  }
  int offV[2][8];
#pragma unroll
  for (int kb = 0; kb < 2; kb++)
#pragma unroll
    for (int dt = 0; dt < 8; dt++) {
      int d = dt * 16 + li;
      offV[kb][dt] = d * 128 + (((kb * 4 + g) ^ (d & 7)) << 4);
    }

  float mrow[4] = {-1e30f, -1e30f, -1e30f, -1e30f};
  float lsum[4] = {0.f, 0.f, 0.f, 0.f};
  floatx4 accO[8] = {};

  int klo = q0 - 1023;
  if (klo < 0) klo = 0;
  klo &= ~63;
  const int nt = (q0 + 128 - klo) >> 6;

  for (int it = 0; it < nt; it++) {
    const int k0 = klo + (it << 6);
    // stage current tile (single buffer)
#pragma unroll
    for (int i = 0; i < 2; i++) GLDS16(gK[i] + (size_t)k0 * 1024, (char*)Ks + ldsOff[i]);
#pragma unroll
    for (int i = 0; i < 2; i++) GLDS16(gV[i] + k0, (char*)Vs + ldsOff[i]);
    asm volatile("s_waitcnt vmcnt(0)" ::: "memory");
    __builtin_amdgcn_s_barrier();

    if (k0 <= qw + 15 && k0 + 63 >= qw - 1023) {
      const char* kb = (const char*)Ks;
      const char* vb = (const char*)Vs;
      floatx4 s[4] = {};
      __builtin_amdgcn_s_setprio(1);
#pragma unroll
      for (int kk = 0; kk < 4; kk++)
#pragma unroll
        for (int n = 0; n < 4; n++) {
          short8 kf = *(const short8*)(kb + offK[n][kk]);
          s[n] = __builtin_amdgcn_mfma_f32_16x16x32_bf16(qf[kk], kf, s[n], 0, 0, 0);
        }
      __builtin_amdgcn_s_setprio(0);
      const bool full = (k0 + 63 <= qw) && (k0 >= qw + 15 - 1023);
      if (!full) {
#pragma unroll
        for (int n = 0; n < 4; n++) {
          const int kc = k0 + n * 16 + li;
#pragma unroll
          for (int r = 0; r < 4; r++) {
            const int qr = qw + 4 * g + r;
            if (kc > qr || qr - kc > 1023) s[n][r] = -__builtin_inff();
          }
        }
      }
      float rm[4];
#pragma unroll
      for (int r = 0; r < 4; r++)
        rm[r] = fmaxf(fmaxf(s[0][r], s[1][r]), fmaxf(s[2][r], s[3][r]));
#pragma unroll
      for (int msk = 1; msk <= 8; msk <<= 1)
#pragma unroll
        for (int r = 0; r < 4; r++) rm[r] = fmaxf(rm[r], __shfl_xor(rm[r], msk));
      float al[4];
#pragma unroll
      for (int r = 0; r < 4; r++) {
        float mn = fmaxf(mrow[r], rm[r]);
        al[r] = __expf(mrow[r] - mn);
        mrow[r] = mn;
        lsum[r] *= al[r];
      }
#pragma unroll
      for (int dt = 0; dt < 8; dt++)
#pragma unroll
        for (int r = 0; r < 4; r++) accO[dt][r] *= al[r];
      float rs[4] = {0.f, 0.f, 0.f, 0.f};
      u16* pw = &Ps[w][0];
#pragma unroll
      for (int n = 0; n < 4; n++)
#pragma unroll
        for (int r = 0; r < 4; r++) {
          float p = __expf(s[n][r] - mrow[r]);
          rs[r] += p;
          pw[(4 * g + r) * 68 + n * 16 + li] = f2bf(p);
        }
#pragma unroll
      for (int msk = 1; msk <= 8; msk <<= 1)
#pragma unroll
        for (int r = 0; r < 4; r++) rs[r] += __shfl_xor(rs[r], msk);
#pragma unroll
      for (int r = 0; r < 4; r++) lsum[r] += rs[r];
      short8 pa[2];
#pragma unroll
      for (int kbi = 0; kbi < 2; kbi++)
        pa[kbi] = *(const short8*)((const char*)&Ps[w][0] + li * 136 + kbi * 64 + g * 16);
      __builtin_amdgcn_s_setprio(1);
#pragma unroll
      for (int kbi = 0; kbi < 2; kbi++)
#pragma unroll
        for (int dt = 0; dt < 8; dt++) {
          short8 vf = *(const short8*)(vb + offV[kbi][dt]);
          accO[dt] = __builtin_amdgcn_mfma_f32_16x16x32_bf16(pa[kbi], vf, accO[dt], 0, 0, 0);
        }
      __builtin_amdgcn_s_setprio(0);
    }
    __builtin_amdgcn_s_barrier();  // all reads done before next tile's stage
  }

  float inv[4];
#pragma unroll
  for (int r = 0; r < 4; r++) inv[r] = 1.0f / lsum[r];
#pragma unroll
  for (int dt = 0; dt < 8; dt++)
#pragma unroll
    for (int r = 0; r < 4; r++)
      O[(size_t)(qw + 4 * g + r) * 4096 + h * 128 + dt * 16 + li] =
          f2bf(accO[dt][r] * inv[r]);
}

// -------------------------------------------------------------- launch ----
extern "C" void kernel_launch(void* const* d_in, const int* in_sizes, int n_in,
                              void* d_out, int out_size, void* d_ws, size_t ws_size,
                              hipStream_t stream) {
  const float* x    = (const float*)d_in[0];
  const float* wq   = (const float*)d_in[1];
  const float* wk   = (const float*)d_in[2];
  const float* wv   = (const float*)d_in[3];
  const float* wo   = (const float*)d_in[4];
  const float* fcos = (const float*)d_in[5];
  const float* fsin = (const float*)d_in[6];

  u16* ws  = (u16*)d_ws;
  u16* xb  = ws;               // 2048x4096
  u16* wqb = xb + 8388608;     // 4096x4096  } contiguous 6144x4096 concat
  u16* wkb = wqb + 16777216;   // 1024x4096  }
  u16* wvb = wkb + 4194304;    // 1024x4096  }
  u16* wob = wvb + 4194304;    // 4096x4096
  u16* Qb  = wob + 16777216;   // 2048x4096
  u16* Kb  = Qb + 8388608;     // 2048x1024
  u16* Vtb = Kb + 2097152;     // 1024x2048 (V^T)
  u16* AOb = Vtb + 2097152;    // 2048x4096

  cast_in<<<1536, 256, 0, stream>>>(x, wq, wk, wv, xb, wqb, wkb, wvb);
  gemm_t<1><<<256, 512, 0, stream>>>(xb, wqb, Qb, Kb, Vtb, fcos, fsin);
  attn_kernel<<<dim3(16, 32), 512, 0, stream>>>(Qb, Kb, Vtb, AOb, wo, wob);
  gemm_t<0><<<256, 512, 0, stream>>>(AOb, wob, d_out, nullptr, nullptr, nullptr, nullptr);
}

// Round 19
// 285.295 us; speedup vs baseline: 1.0194x; 1.0194x over previous
//
#include <hip/hip_runtime.h>
#include <hip/hip_bf16.h>

// TtAttention: x(2048,4096) -> QKV proj -> RoPE -> windowed causal GQA attention -> O proj.
// QKV GEMM: BM=256 BN=192, 8 waves 4Mx2N, BK=64 flat interior, A 2-buf / B 3-buf,
//   counted vmcnt, 1 barrier/K-tile, 256 blocks, bm = XCD.
// O-proj GEMM: 128x128 tile, 4 waves 2Mx2N, 80KB LDS -> 2 blocks/CU (cross-block
//   TLP hides the per-tile barrier+staging overhead), 512 blocks, 2 m-panels/XCD.
// attn: 8-wave blocks, single-buffered K/V, 3 blocks/CU; fused wo cast.

typedef __attribute__((ext_vector_type(8))) short short8;
typedef __attribute__((ext_vector_type(4))) float floatx4;
typedef unsigned short u16;
typedef unsigned int u32;

__device__ __forceinline__ u16 f2bf(float f) {
  u32 u = __builtin_bit_cast(u32, f);
  u32 r = u + 0x7FFFu + ((u >> 16) & 1u);
  return (u16)(r >> 16);
}

#define GLDS16(g, l)                                                     \
  __builtin_amdgcn_global_load_lds(                                      \
      (const __attribute__((address_space(1))) u32*)(g),                 \
      (__attribute__((address_space(3))) u32*)(l), 16, 0, 0)

#define SB() __builtin_amdgcn_sched_barrier(0)

// ---------------------------------------------------------------- cast ----
// x + wq/wk/wv (wo folded into attn).
__global__ __launch_bounds__(256) void cast_in(
    const float* __restrict__ x, const float* __restrict__ wq,
    const float* __restrict__ wk, const float* __restrict__ wv,
    u16* __restrict__ xb, u16* __restrict__ wqb, u16* __restrict__ wkb,
    u16* __restrict__ wvb) {
  const int tid = blockIdx.x * blockDim.x + threadIdx.x;
  const int stride = gridDim.x * blockDim.x;
  auto seg = [&](const float* __restrict__ in, u16* __restrict__ out, int n4) {
    for (int i = tid; i < n4; i += stride) {
      float4 v = ((const float4*)in)[i];
      ushort4 o;
      o.x = f2bf(v.x); o.y = f2bf(v.y); o.z = f2bf(v.z); o.w = f2bf(v.w);
      ((ushort4*)out)[i] = o;
    }
  };
  seg(x, xb, 2097152);
  seg(wq, wqb, 4194304);
  seg(wk, wkb, 1048576);
  seg(wv, wvb, 1048576);
}

// ------------------------------------------------------------ QKV GEMM ----
// C[m][n] = sum_k A[m][k]*B[n][k].  8 waves (4M x 2N, WR=64, WC=96),
// BM=256 BN=192 BK=64. B = concat[wq;wk;wv], per-frag epilogue
// (Q: RoPE+scale, K: RoPE, V: transposed store). grid 8m x 32n = 256 blocks;
// bm = blockIdx.x & 7 (= XCD, A-panel L2-resident).
// Flat K-tile: reads(kh0) | stage A(t+1) | MFMA | reads(kh1) | stage B(t+2)
// | MFMA; SB-fenced; vmcnt(3) retires {B,A}(t+1), keeps B(t+2) in flight.
__global__ __launch_bounds__(512, 2) void gemm_qkv(
    const u16* __restrict__ A, const u16* __restrict__ B, u16* __restrict__ Cq,
    u16* __restrict__ Ck, u16* __restrict__ Cv, const float* __restrict__ fcos,
    const float* __restrict__ fsin) {
  constexpr int BM = 256, BN = 192;
  constexpr int WR = 64, WC = 96;
  constexpr int MFR = 4, NFR = 6;
  constexpr int ASZ = BM * 128;           // 32KB
  constexpr int BSZ = BN * 128;           // 24KB
  constexpr int NCA = 4, NCB = 3;
  __shared__ u16 lds[(2 * ASZ + 3 * BSZ) / 2];
  const int K = 4096;

  const int bm = blockIdx.x & 7;
  const int bx = blockIdx.x >> 3;
  const int m0 = bm * BM, n0 = bx * BN;

  const int t = threadIdx.x, l = t & 63, w = t >> 6;
  const int li = l & 15, g = l >> 4;
  const int wm = w >> 1, wn = w & 1;

  const int srow = t >> 3;
  const int sslot = (t & 7) ^ (srow & 7);
  const u16* gA = A + (size_t)(m0 + srow) * K + sslot * 8;
  const u16* gB = B + (size_t)(n0 + srow) * K + sslot * 8;
  const int dst = t * 16;

  char* A0p = (char*)lds;
  char* A1p = A0p + ASZ;
  char* B0p = A0p + 2 * ASZ;
  char* B1p = B0p + BSZ;
  char* B2p = B1p + BSZ;

  auto stA = [&](char* base, int kt, int c) {
    GLDS16(gA + (size_t)c * 64 * K + kt, base + c * 8192 + dst);
  };
  auto stB = [&](char* base, int kt, int c) {
    GLDS16(gB + (size_t)c * 64 * K + kt, base + c * 8192 + dst);
  };

  int offA[2][MFR], offB[2][NFR];
#pragma unroll
  for (int kh = 0; kh < 2; kh++) {
#pragma unroll
    for (int mf = 0; mf < MFR; mf++) {
      int r = wm * WR + mf * 16 + li;
      offA[kh][mf] = r * 128 + ((((kh << 2) | g) ^ (r & 7)) << 4);
    }
#pragma unroll
    for (int nf = 0; nf < NFR; nf++) {
      int r = wn * WC + nf * 16 + li;
      offB[kh][nf] = r * 128 + ((((kh << 2) | g) ^ (r & 7)) << 4);
    }
  }

  floatx4 acc[MFR][NFR] = {};
  const int NT = K / 64;

#pragma unroll
  for (int c = 0; c < NCB; c++) stB(B0p, 0, c);
#pragma unroll
  for (int c = 0; c < NCA; c++) stA(A0p, 0, c);
#pragma unroll
  for (int c = 0; c < NCB; c++) stB(B1p, 64, c);
  asm volatile("s_waitcnt vmcnt(3)" ::: "memory");
  __builtin_amdgcn_s_barrier();

  for (int tt = 0; tt < NT; ++tt) {
    SB();
    const char* Ac = A0p;
    const char* Bc = B0p;
    const int kt1 = (tt + 1) * 64, kt2 = (tt + 2) * 64;
    const bool s1 = (tt + 1 < NT), s2 = (tt + 2 < NT);

    short8 a0[MFR], b0[NFR], a1[MFR], b1[NFR];
#pragma unroll
    for (int nf = 0; nf < NFR; nf++) b0[nf] = *(const short8*)(Bc + offB[0][nf]);
#pragma unroll
    for (int mf = 0; mf < MFR; mf++) a0[mf] = *(const short8*)(Ac + offA[0][mf]);
    if (s1) {
#pragma unroll
      for (int c = 0; c < NCA; c++) stA(A1p, kt1, c);
    }
#pragma unroll
    for (int mf = 0; mf < MFR; mf++)
#pragma unroll
      for (int nf = 0; nf < NFR; nf++)
        acc[mf][nf] = __builtin_amdgcn_mfma_f32_16x16x32_bf16(a0[mf], b0[nf], acc[mf][nf], 0, 0, 0);
#pragma unroll
    for (int nf = 0; nf < NFR; nf++) b1[nf] = *(const short8*)(Bc + offB[1][nf]);
#pragma unroll
    for (int mf = 0; mf < MFR; mf++) a1[mf] = *(const short8*)(Ac + offA[1][mf]);
    if (s2) {
#pragma unroll
      for (int c = 0; c < NCB; c++) stB(B2p, kt2, c);
    }
#pragma unroll
    for (int mf = 0; mf < MFR; mf++)
#pragma unroll
      for (int nf = 0; nf < NFR; nf++)
        acc[mf][nf] = __builtin_amdgcn_mfma_f32_16x16x32_bf16(a1[mf], b1[nf], acc[mf][nf], 0, 0, 0);
    SB();
    if (s2)      asm volatile("s_waitcnt vmcnt(3)" ::: "memory");
    else if (s1) asm volatile("s_waitcnt vmcnt(0)" ::: "memory");
    __builtin_amdgcn_s_barrier();

    char* tmpA = A0p; A0p = A1p; A1p = tmpA;
    char* tmpB = B0p; B0p = B1p; B1p = B2p; B2p = tmpB;
  }

  const float scale = 0.08838834764831845f;  // 128^-0.5
#pragma unroll
  for (int mf = 0; mf < MFR; mf++) {
#pragma unroll
    for (int nf = 0; nf < NFR; nf++) {
      const int row0 = m0 + wm * WR + mf * 16 + 4 * g;
      const int c = n0 + wn * WC + nf * 16 + li;
      if (c < 5120) {  // Q or K: RoPE (+scale for Q)
        const int hd = c & 127;
        const int pp = hd >> 1;
        const bool even = (hd & 1) == 0;
#pragma unroll
        for (int r = 0; r < 4; r++) {
          const int row = row0 + r;
          float cv = fcos[row * 64 + pp];
          float sv = fsin[row * 64 + pp];
          float v = acc[mf][nf][r];
          float pv = __shfl_xor(v, 1);
          float o = even ? (v * cv - pv * sv) : (pv * sv + v * cv);
          if (c < 4096) {
            Cq[(size_t)row * 4096 + c] = f2bf(o * scale);
          } else {
            Ck[(size_t)row * 1024 + (c - 4096)] = f2bf(o);
          }
        }
      } else {  // V: transposed bf16 store to V^T (ld 2048)
        u32 lo = (u32)f2bf(acc[mf][nf][0]) | ((u32)f2bf(acc[mf][nf][1]) << 16);
        u32 hi = (u32)f2bf(acc[mf][nf][2]) | ((u32)f2bf(acc[mf][nf][3]) << 16);
        uint2 val; val.x = lo; val.y = hi;
        *(uint2*)(&Cv[(size_t)(c - 5120) * 2048 + row0]) = val;
      }
    }
  }
}

// --------------------------------------------------------- O-proj GEMM ----
// C[m][n] = sum_k A[m][k]*wo[n][k], fp32 store. 128x128 tile, 4 waves (2Mx2N,
// WR=WC=64), BK=64. LDS: A x2 (32KB) + B x3 (48KB) = 80KB -> 2 blocks/CU:
// two independent blocks per CU overlap each other's staging waits/barriers
// (cross-block TLP — the r17 attn mechanism applied to the GEMM).
// grid 512 blocks; xcd = bid&7 owns two 128-row A-panels (L2-resident).
// Staging chunk = 4KB (32 rows x 128B, 256 thr x 16B). FIFO at tile end:
// [B(t+1) x4, A(t+1) x4, B(t+2) x4] -> vmcnt(4) retires {B,A}(t+1).
__global__ __launch_bounds__(256, 2) void gemm_o(
    const u16* __restrict__ A, const u16* __restrict__ B, float* __restrict__ C) {
  constexpr int ASZ = 128 * 128;          // 16KB
  constexpr int BSZ = 128 * 128;          // 16KB
  __shared__ u16 lds[(2 * ASZ + 3 * BSZ) / 2];  // 80KB
  const int K = 4096;

  const int xcd = blockIdx.x & 7;
  const int j = blockIdx.x >> 3;          // 0..63
  const int bm = xcd * 2 + (j & 1);       // 0..15
  const int bx = j >> 1;                  // 0..31
  const int m0 = bm * 128, n0 = bx * 128;

  const int t = threadIdx.x, l = t & 63, w = t >> 6;   // w 0..3
  const int li = l & 15, g = l >> 4;
  const int wm = w >> 1, wn = w & 1;

  const int srow = t >> 3;                // 0..31
  const int sslot = (t & 7) ^ (srow & 7);
  const u16* gA = A + (size_t)(m0 + srow) * K + sslot * 8;
  const u16* gB = B + (size_t)(n0 + srow) * K + sslot * 8;
  const int dst = t * 16;

  char* A0p = (char*)lds;
  char* A1p = A0p + ASZ;
  char* B0p = A0p + 2 * ASZ;
  char* B1p = B0p + BSZ;
  char* B2p = B1p + BSZ;

  auto stA = [&](char* base, int kt, int c) {
    GLDS16(gA + (size_t)c * 32 * K + kt, base + c * 4096 + dst);
  };
  auto stB = [&](char* base, int kt, int c) {
    GLDS16(gB + (size_t)c * 32 * K + kt, base + c * 4096 + dst);
  };

  int offA[2][4], offB[2][4];
#pragma unroll
  for (int kh = 0; kh < 2; kh++) {
#pragma unroll
    for (int mf = 0; mf < 4; mf++) {
      int r = wm * 64 + mf * 16 + li;
      offA[kh][mf] = r * 128 + ((((kh << 2) | g) ^ (r & 7)) << 4);
    }
#pragma unroll
    for (int nf = 0; nf < 4; nf++) {
      int r = wn * 64 + nf * 16 + li;
      offB[kh][nf] = r * 128 + ((((kh << 2) | g) ^ (r & 7)) << 4);
    }
  }

  floatx4 acc[4][4] = {};
  const int NT = K / 64;

#pragma unroll
  for (int c = 0; c < 4; c++) stB(B0p, 0, c);
#pragma unroll
  for (int c = 0; c < 4; c++) stA(A0p, 0, c);
#pragma unroll
  for (int c = 0; c < 4; c++) stB(B1p, 64, c);
  asm volatile("s_waitcnt vmcnt(4)" ::: "memory");
  __builtin_amdgcn_s_barrier();

  for (int tt = 0; tt < NT; ++tt) {
    SB();
    const char* Ac = A0p;
    const char* Bc = B0p;
    const int kt1 = (tt + 1) * 64, kt2 = (tt + 2) * 64;
    const bool s1 = (tt + 1 < NT), s2 = (tt + 2 < NT);

    short8 a0[4], b0[4], a1[4], b1[4];
#pragma unroll
    for (int mf = 0; mf < 4; mf++) a0[mf] = *(const short8*)(Ac + offA[0][mf]);
#pragma unroll
    for (int nf = 0; nf < 4; nf++) b0[nf] = *(const short8*)(Bc + offB[0][nf]);
    if (s1) {
#pragma unroll
      for (int c = 0; c < 4; c++) stA(A1p, kt1, c);
    }
#pragma unroll
    for (int mf = 0; mf < 4; mf++)
#pragma unroll
      for (int nf = 0; nf < 4; nf++)
        acc[mf][nf] = __builtin_amdgcn_mfma_f32_16x16x32_bf16(a0[mf], b0[nf], acc[mf][nf], 0, 0, 0);
#pragma unroll
    for (int mf = 0; mf < 4; mf++) a1[mf] = *(const short8*)(Ac + offA[1][mf]);
#pragma unroll
    for (int nf = 0; nf < 4; nf++) b1[nf] = *(const short8*)(Bc + offB[1][nf]);
    if (s2) {
#pragma unroll
      for (int c = 0; c < 4; c++) stB(B2p, kt2, c);
    }
#pragma unroll
    for (int mf = 0; mf < 4; mf++)
#pragma unroll
      for (int nf = 0; nf < 4; nf++)
        acc[mf][nf] = __builtin_amdgcn_mfma_f32_16x16x32_bf16(a1[mf], b1[nf], acc[mf][nf], 0, 0, 0);
    SB();
    if (s2)      asm volatile("s_waitcnt vmcnt(4)" ::: "memory");
    else if (s1) asm volatile("s_waitcnt vmcnt(0)" ::: "memory");
    __builtin_amdgcn_s_barrier();

    char* tmpA = A0p; A0p = A1p; A1p = tmpA;
    char* tmpB = B0p; B0p = B1p; B1p = B2p; B2p = tmpB;
  }

#pragma unroll
  for (int mf = 0; mf < 4; mf++) {
#pragma unroll
    for (int nf = 0; nf < 4; nf++) {
      const int row0 = m0 + wm * 64 + mf * 16 + 4 * g;
      const int c = n0 + wn * 64 + nf * 16 + li;
#pragma unroll
      for (int r = 0; r < 4; r++) C[(size_t)(row0 + r) * 4096 + c] = acc[mf][nf][r];
    }
  }
}

// ----------------------------------------------------------- attention ----
// Q (2048,4096) bf16 (RoPE'd, pre-scaled), K (2048,1024) bf16 (RoPE'd),
// Vt (1024,2048) bf16 = V^T. O (2048,4096) bf16.
// 8-wave blocks: grid (S/128, H) = (16,32); wave w owns q rows [q0+16w, +16).
// SINGLE-buffered K/V tiles (KVBLK=64) shared by all 8 waves; 50KB LDS ->
// 3 blocks/CU — cross-block TLP replaces the double-buffer.
// Per tile: stage -> vmcnt(0) -> barrier -> compute -> barrier.
// FUSED: wo fp32->bf16 cast at kernel top (512 blk x 512 thr x 16 float4).
__global__ __launch_bounds__(512, 2) void attn_kernel(const u16* __restrict__ Q,
                                                      const u16* __restrict__ K,
                                                      const u16* __restrict__ Vt,
                                                      u16* __restrict__ O,
                                                      const float* __restrict__ wo,
                                                      u16* __restrict__ wob) {
  __shared__ u16 Ks[64 * 128];   // [k][d], 256B rows, slot ^= row&7
  __shared__ u16 Vs[128 * 64];   // [d][k], 128B rows, slot ^= row&7
  __shared__ u16 Ps[8][16 * 68]; // per-wave P relayout, stride 68 (136B)

  // ---- fused wo cast ----
  {
    const int gid = (blockIdx.y * gridDim.x + blockIdx.x) * 512 + threadIdx.x;
#pragma unroll 4
    for (int i = 0; i < 16; i++) {
      const size_t idx = (size_t)gid + (size_t)i * 262144;
      float4 v = ((const float4*)wo)[idx];
      ushort4 o;
      o.x = f2bf(v.x); o.y = f2bf(v.y); o.z = f2bf(v.z); o.w = f2bf(v.w);
      ((ushort4*)wob)[idx] = o;
    }
  }

  const int t = threadIdx.x, l = t & 63, w = t >> 6;   // w in 0..7
  const int li = l & 15, g = l >> 4;
  const int q0 = blockIdx.x * 128;
  const int h = blockIdx.y;
  const int kvh = h >> 2;
  const int qw = q0 + w * 16;

  short8 qf[4];
  {
    const u16* qp = Q + (size_t)(qw + li) * 4096 + h * 128 + g * 8;
#pragma unroll
    for (int kk = 0; kk < 4; kk++) qf[kk] = *(const short8*)(qp + kk * 32);
  }

  const u16* gK[2];
  const u16* gV[2];
  int ldsOff[2];
#pragma unroll
  for (int i = 0; i < 2; i++) {
    int rK = (2 * w + i) * 4 + (l >> 4);
    int sK = (l & 15) ^ (rK & 7);
    gK[i] = K + (size_t)rK * 1024 + kvh * 128 + sK * 8;
    int rV = (2 * w + i) * 8 + (l >> 3);
    int sV = (l & 7) ^ (rV & 7);
    gV[i] = Vt + (size_t)(kvh * 128 + rV) * 2048 + sV * 8;
    ldsOff[i] = (2 * w + i) * 1024;
  }

  int offK[4][4];
#pragma unroll
  for (int n = 0; n < 4; n++) {
    int r = 16 * n + li;
#pragma unroll
    for (int kk = 0; kk < 4; kk++)
      offK[n][kk] = r * 256 + (((kk * 4 + g) ^ (r & 7)) << 4);
  }
  int offV[2][8];
#pragma unroll
  for (int kb = 0; kb < 2; kb++)
#pragma unroll
    for (int dt = 0; dt < 8; dt++) {
      int d = dt * 16 + li;
      offV[kb][dt] = d * 128 + (((kb * 4 + g) ^ (d & 7)) << 4);
    }

  float mrow[4] = {-1e30f, -1e30f, -1e30f, -1e30f};
  float lsum[4] = {0.f, 0.f, 0.f, 0.f};
  floatx4 accO[8] = {};

  int klo = q0 - 1023;
  if (klo < 0) klo = 0;
  klo &= ~63;
  const int nt = (q0 + 128 - klo) >> 6;

  for (int it = 0; it < nt; it++) {
    const int k0 = klo + (it << 6);
#pragma unroll
    for (int i = 0; i < 2; i++) GLDS16(gK[i] + (size_t)k0 * 1024, (char*)Ks + ldsOff[i]);
#pragma unroll
    for (int i = 0; i < 2; i++) GLDS16(gV[i] + k0, (char*)Vs + ldsOff[i]);
    asm volatile("s_waitcnt vmcnt(0)" ::: "memory");
    __builtin_amdgcn_s_barrier();

    if (k0 <= qw + 15 && k0 + 63 >= qw - 1023) {
      const char* kb = (const char*)Ks;
      const char* vb = (const char*)Vs;
      floatx4 s[4] = {};
      __builtin_amdgcn_s_setprio(1);
#pragma unroll
      for (int kk = 0; kk < 4; kk++)
#pragma unroll
        for (int n = 0; n < 4; n++) {
          short8 kf = *(const short8*)(kb + offK[n][kk]);
          s[n] = __builtin_amdgcn_mfma_f32_16x16x32_bf16(qf[kk], kf, s[n], 0, 0, 0);
        }
      __builtin_amdgcn_s_setprio(0);
      const bool full = (k0 + 63 <= qw) && (k0 >= qw + 15 - 1023);
      if (!full) {
#pragma unroll
        for (int n = 0; n < 4; n++) {
          const int kc = k0 + n * 16 + li;
#pragma unroll
          for (int r = 0; r < 4; r++) {
            const int qr = qw + 4 * g + r;
            if (kc > qr || qr - kc > 1023) s[n][r] = -__builtin_inff();
          }
        }
      }
      float rm[4];
#pragma unroll
      for (int r = 0; r < 4; r++)
        rm[r] = fmaxf(fmaxf(s[0][r], s[1][r]), fmaxf(s[2][r], s[3][r]));
#pragma unroll
      for (int msk = 1; msk <= 8; msk <<= 1)
#pragma unroll
        for (int r = 0; r < 4; r++) rm[r] = fmaxf(rm[r], __shfl_xor(rm[r], msk));
      float al[4];
#pragma unroll
      for (int r = 0; r < 4; r++) {
        float mn = fmaxf(mrow[r], rm[r]);
        al[r] = __expf(mrow[r] - mn);
        mrow[r] = mn;
        lsum[r] *= al[r];
      }
#pragma unroll
      for (int dt = 0; dt < 8; dt++)
#pragma unroll
        for (int r = 0; r < 4; r++) accO[dt][r] *= al[r];
      float rs[4] = {0.f, 0.f, 0.f, 0.f};
      u16* pw = &Ps[w][0];
#pragma unroll
      for (int n = 0; n < 4; n++)
#pragma unroll
        for (int r = 0; r < 4; r++) {
          float p = __expf(s[n][r] - mrow[r]);
          rs[r] += p;
          pw[(4 * g + r) * 68 + n * 16 + li] = f2bf(p);
        }
#pragma unroll
      for (int msk = 1; msk <= 8; msk <<= 1)
#pragma unroll
        for (int r = 0; r < 4; r++) rs[r] += __shfl_xor(rs[r], msk);
#pragma unroll
      for (int r = 0; r < 4; r++) lsum[r] += rs[r];
      short8 pa[2];
#pragma unroll
      for (int kbi = 0; kbi < 2; kbi++)
        pa[kbi] = *(const short8*)((const char*)&Ps[w][0] + li * 136 + kbi * 64 + g * 16);
      __builtin_amdgcn_s_setprio(1);
#pragma unroll
      for (int kbi = 0; kbi < 2; kbi++)
#pragma unroll
        for (int dt = 0; dt < 8; dt++) {
          short8 vf = *(const short8*)(vb + offV[kbi][dt]);
          accO[dt] = __builtin_amdgcn_mfma_f32_16x16x32_bf16(pa[kbi], vf, accO[dt], 0, 0, 0);
        }
      __builtin_amdgcn_s_setprio(0);
    }
    __builtin_amdgcn_s_barrier();
  }

  float inv[4];
#pragma unroll
  for (int r = 0; r < 4; r++) inv[r] = 1.0f / lsum[r];
#pragma unroll
  for (int dt = 0; dt < 8; dt++)
#pragma unroll
    for (int r = 0; r < 4; r++)
      O[(size_t)(qw + 4 * g + r) * 4096 + h * 128 + dt * 16 + li] =
          f2bf(accO[dt][r] * inv[r]);
}

// -------------------------------------------------------------- launch ----
extern "C" void kernel_launch(void* const* d_in, const int* in_sizes, int n_in,
                              void* d_out, int out_size, void* d_ws, size_t ws_size,
                              hipStream_t stream) {
  const float* x    = (const float*)d_in[0];
  const float* wq   = (const float*)d_in[1];
  const float* wk   = (const float*)d_in[2];
  const float* wv   = (const float*)d_in[3];
  const float* wo   = (const float*)d_in[4];
  const float* fcos = (const float*)d_in[5];
  const float* fsin = (const float*)d_in[6];

  u16* ws  = (u16*)d_ws;
  u16* xb  = ws;               // 2048x4096
  u16* wqb = xb + 8388608;     // 4096x4096  } contiguous 6144x4096 concat
  u16* wkb = wqb + 16777216;   // 1024x4096  }
  u16* wvb = wkb + 4194304;    // 1024x4096  }
  u16* wob = wvb + 4194304;    // 4096x4096
  u16* Qb  = wob + 16777216;   // 2048x4096
  u16* Kb  = Qb + 8388608;     // 2048x1024
  u16* Vtb = Kb + 2097152;     // 1024x2048 (V^T)
  u16* AOb = Vtb + 2097152;    // 2048x4096

  cast_in<<<1536, 256, 0, stream>>>(x, wq, wk, wv, xb, wqb, wkb, wvb);
  gemm_qkv<<<256, 512, 0, stream>>>(xb, wqb, Qb, Kb, Vtb, fcos, fsin);
  attn_kernel<<<dim3(16, 32), 512, 0, stream>>>(Qb, Kb, Vtb, AOb, wo, wob);
  gemm_o<<<512, 256, 0, stream>>>(AOb, wob, (float*)d_out);
}